// Round 5
// baseline (214.461 us; speedup 1.0000x reference)
//
#include <hip/hip_runtime.h>
#include <hip/hip_fp16.h>

// HyperedgeAggregator: out[s, :] = mean over members i with segment_ids[i]==s
// of node_embeddings[node_indices[i], :].
//
// NUM_NODES=100000, EMBED_DIM=256, NUM_EDGES=16384, TOTAL=524288, seg_ids SORTED.
//
// R5 model: gather bound by random-access latency/L3 fabric with ~8% L2 hit
// (51MB fp16 table vs 4MiB per-XCD L2). Lever: DIMENSION-SLICED fp16 table
// [8][NUM_NODES][32] in d_ws; one slice = 64 B = 1 line per member. Blocks pick
// slice = blockIdx&7; round-robin block->XCD dispatch pins each 6.4MB sub-table
// to one XCD's L2 (~60% hit vs 8%). Line count unchanged, latency drops.
//
//   1) prep_kernel (fused): fp32->fp16 sliced transpose + seg_start bounds
//   2) agg_sliced:  grid 4096x8; wave=(segment,slice); 64-index batch +
//      __shfl broadcast; 8 independent line-gathers in flight per wave;
//      3x shfl_xor cross-member reduce; lanes 0..7 store 128 B.

#define EMBED_DIM 256
#define NUM_EDGES 16384
#define TOTAL_MEM 524288
#define NUM_NODES 100000

#define TAB16_BYTES ((size_t)NUM_NODES * EMBED_DIM * 2)         // 51,200,000
#define BOUNDS_BYTES ((size_t)(NUM_EDGES + 1) * sizeof(int))    // 65,540

#define CONV_BLOCKS   12500   // NUM_NODES*32 threads / 256  (exact)
#define BOUNDS_BLOCKS 2048    // TOTAL_MEM / 256              (exact)

// Fused: sliced fp16 transpose-convert + segment bounds.
__global__ __launch_bounds__(256) void prep_kernel(
    const float4* __restrict__ emb4,      // fp32 table as float4 [NUM_NODES*64]
    uint4*        __restrict__ tab,       // sliced fp16: [8][NUM_NODES][4] uint4
    const int*    __restrict__ seg_ids,   // [TOTAL_MEM], sorted
    int*          __restrict__ seg_start) // [NUM_EDGES+1]
{
    const int b = blockIdx.x;
    if (b < CONV_BLOCKS) {
        const int u  = b * 256 + threadIdx.x;   // [0, NUM_NODES*32)
        const int n  = u >> 5;                  // node
        const int d8 = u & 31;                  // dim-octet within row
        // coalesced read: 32 B per thread, 2 KB per wave
        float4 a = emb4[(size_t)n * 64 + d8 * 2];
        float4 c = emb4[(size_t)n * 64 + d8 * 2 + 1];
        __half2 h0 = __floats2half2_rn(a.x, a.y);
        __half2 h1 = __floats2half2_rn(a.z, a.w);
        __half2 h2 = __floats2half2_rn(c.x, c.y);
        __half2 h3 = __floats2half2_rn(c.z, c.w);
        uint4 o;
        o.x = *reinterpret_cast<unsigned int*>(&h0);
        o.y = *reinterpret_cast<unsigned int*>(&h1);
        o.z = *reinterpret_cast<unsigned int*>(&h2);
        o.w = *reinterpret_cast<unsigned int*>(&h3);
        const int p = d8 >> 2;   // slice
        const int q = d8 & 3;    // uint4 within 64-B row-slice
        // 4 consecutive threads write one full 64-B line
        tab[((size_t)p * NUM_NODES + n) * 4 + q] = o;
    } else {
        const int i = (b - CONV_BLOCKS) * 256 + threadIdx.x;
        if (i >= TOTAL_MEM) return;
        const int cur  = seg_ids[i];
        const int prev = (i == 0) ? -1 : seg_ids[i - 1];
        for (int s = prev + 1; s <= cur; ++s) seg_start[s] = i;
        if (i == TOTAL_MEM - 1) {
            for (int s = cur + 1; s <= NUM_EDGES; ++s) seg_start[s] = TOTAL_MEM;
        }
    }
}

__global__ __launch_bounds__(256) void agg_sliced_kernel(
    const uint2* __restrict__ tab,        // sliced fp16: [8][NUM_NODES][8] uint2
    const int*   __restrict__ node_idx,   // [TOTAL_MEM]
    const int*   __restrict__ seg_start,  // [NUM_EDGES+1]
    float*       __restrict__ out)        // [NUM_EDGES, EMBED_DIM]
{
    const int wave  = threadIdx.x >> 6;          // 4 waves per block
    const int lane  = threadIdx.x & 63;
    const int slice = blockIdx.x & 7;            // -> XCD via round-robin dispatch
    const int seg   = (blockIdx.x >> 3) * 4 + wave;
    if (seg >= NUM_EDGES) return;

    const int start = seg_start[seg];
    const int end   = seg_start[seg + 1];

    const uint2* sub = tab + (size_t)slice * NUM_NODES * 8;
    const int m   = lane >> 3;   // member-in-group 0..7
    const int d8r = lane & 7;    // uint2 within 64-B row-slice

    float4 acc = make_float4(0.f, 0.f, 0.f, 0.f);

    for (int i = start; i < end; i += 64) {
        const int batch = min(end - i, 64);
        const int my = (lane < batch) ? node_idx[i + lane] : 0;  // coalesced

        uint2 v[8];
        #pragma unroll
        for (int g = 0; g < 8; ++g) {
            v[g] = make_uint2(0u, 0u);
            const int msel = g * 8 + m;
            const int n = __shfl(my, msel);
            if (msel < batch)
                v[g] = sub[(size_t)n * 8 + d8r];   // 1 line per member-group
        }
        #pragma unroll
        for (int g = 0; g < 8; ++g) {
            __half2 h0 = *reinterpret_cast<__half2*>(&v[g].x);
            __half2 h1 = *reinterpret_cast<__half2*>(&v[g].y);
            float2 f0 = __half22float2(h0);
            float2 f1 = __half22float2(h1);
            acc.x += f0.x; acc.y += f0.y;
            acc.z += f1.x; acc.w += f1.y;
        }
    }

    // reduce across the 8 member-lanes (stride 8,16,32 butterfly)
    #pragma unroll
    for (int s = 8; s <= 32; s <<= 1) {
        acc.x += __shfl_xor(acc.x, s);
        acc.y += __shfl_xor(acc.y, s);
        acc.z += __shfl_xor(acc.z, s);
        acc.w += __shfl_xor(acc.w, s);
    }

    const float cnt = (end > start) ? (float)(end - start) : 1.0f;
    acc.x /= cnt; acc.y /= cnt; acc.z /= cnt; acc.w /= cnt;

    if (lane < 8)
        ((float4*)(out + (size_t)seg * EMBED_DIM + slice * 32))[lane] = acc;
}

// ---------- fp32 fallback paths (small ws) ----------

__global__ __launch_bounds__(256) void seg_bounds_kernel(
    const int* __restrict__ seg_ids, int* __restrict__ seg_start)
{
    const int i = blockIdx.x * blockDim.x + threadIdx.x;
    if (i >= TOTAL_MEM) return;
    const int cur  = seg_ids[i];
    const int prev = (i == 0) ? -1 : seg_ids[i - 1];
    for (int s = prev + 1; s <= cur; ++s) seg_start[s] = i;
    if (i == TOTAL_MEM - 1) {
        for (int s = cur + 1; s <= NUM_EDGES; ++s) seg_start[s] = TOTAL_MEM;
    }
}

__global__ __launch_bounds__(256) void hyperedge_agg_kernel(
    const float* __restrict__ emb,
    const int*   __restrict__ node_idx,
    const int*   __restrict__ seg_start,
    float*       __restrict__ out)
{
    const int wave = threadIdx.x >> 6;
    const int lane = threadIdx.x & 63;
    const int seg  = blockIdx.x * 4 + wave;
    if (seg >= NUM_EDGES) return;

    const int start = seg_start[seg];
    const int end   = seg_start[seg + 1];

    float4 acc = make_float4(0.f, 0.f, 0.f, 0.f);
    int i = start;
    while (i < end) {
        const int batch = min(end - i, 64);
        const int my = (lane < batch) ? node_idx[i + lane] : 0;
        for (int j = 0; j < batch; j += 8) {
            const int mm = min(batch - j, 8);
            float4 v[8];
            #pragma unroll
            for (int t = 0; t < 8; ++t)
                if (t < mm) {
                    const int n = __shfl(my, j + t);
                    v[t] = ((const float4*)(emb + (size_t)n * EMBED_DIM))[lane];
                }
            #pragma unroll
            for (int t = 0; t < 8; ++t)
                if (t < mm) {
                    acc.x += v[t].x; acc.y += v[t].y;
                    acc.z += v[t].z; acc.w += v[t].w;
                }
        }
        i += batch;
    }
    const float cnt = (end > start) ? (float)(end - start) : 1.0f;
    acc.x /= cnt; acc.y /= cnt; acc.z /= cnt; acc.w /= cnt;
    ((float4*)(out + (size_t)seg * EMBED_DIM))[lane] = acc;
}

__global__ __launch_bounds__(256) void hyperedge_agg_bsearch_kernel(
    const float* __restrict__ emb,
    const int*   __restrict__ node_idx,
    const int*   __restrict__ seg_ids,
    float*       __restrict__ out)
{
    const int wave = threadIdx.x >> 6;
    const int lane = threadIdx.x & 63;
    const int seg  = blockIdx.x * 4 + wave;
    if (seg >= NUM_EDGES) return;

    int lo = 0, hi = TOTAL_MEM;
    while (lo < hi) {
        int mid = (lo + hi) >> 1;
        if (seg_ids[mid] < seg) lo = mid + 1; else hi = mid;
    }
    const int start = lo;
    hi = TOTAL_MEM;
    while (lo < hi) {
        int mid = (lo + hi) >> 1;
        if (seg_ids[mid] < seg + 1) lo = mid + 1; else hi = mid;
    }
    const int end = lo;

    float4 acc = make_float4(0.f, 0.f, 0.f, 0.f);
    for (int i = start; i < end; ++i) {
        const int n = node_idx[i];
        float4 v = ((const float4*)(emb + (size_t)n * EMBED_DIM))[lane];
        acc.x += v.x; acc.y += v.y; acc.z += v.z; acc.w += v.w;
    }
    const float cnt = (end > start) ? (float)(end - start) : 1.0f;
    acc.x /= cnt; acc.y /= cnt; acc.z /= cnt; acc.w /= cnt;
    ((float4*)(out + (size_t)seg * EMBED_DIM))[lane] = acc;
}

extern "C" void kernel_launch(void* const* d_in, const int* in_sizes, int n_in,
                              void* d_out, int out_size, void* d_ws, size_t ws_size,
                              hipStream_t stream) {
    const float* emb      = (const float*)d_in[0];
    const int*   node_idx = (const int*)d_in[1];
    const int*   seg_ids  = (const int*)d_in[2];
    float*       out      = (float*)d_out;

    if (ws_size >= TAB16_BYTES + BOUNDS_BYTES) {
        // Layout: [sliced fp16 table | seg_start]
        uint4* tab16     = (uint4*)d_ws;
        int*   seg_start = (int*)((char*)d_ws + TAB16_BYTES);

        prep_kernel<<<CONV_BLOCKS + BOUNDS_BLOCKS, 256, 0, stream>>>(
            (const float4*)emb, tab16, seg_ids, seg_start);
        agg_sliced_kernel<<<(NUM_EDGES / 4) * 8, 256, 0, stream>>>(
            (const uint2*)tab16, node_idx, seg_start, out);
    } else if (ws_size >= BOUNDS_BYTES) {
        int* seg_start = (int*)d_ws;
        seg_bounds_kernel<<<(TOTAL_MEM + 255) / 256, 256, 0, stream>>>(seg_ids, seg_start);
        hyperedge_agg_kernel<<<NUM_EDGES / 4, 256, 0, stream>>>(emb, node_idx, seg_start, out);
    } else {
        hyperedge_agg_bsearch_kernel<<<NUM_EDGES / 4, 256, 0, stream>>>(emb, node_idx, seg_ids, out);
    }
}

// Round 6
// 206.541 us; speedup vs baseline: 1.0383x; 1.0383x over previous
//
#include <hip/hip_runtime.h>
#include <hip/hip_fp16.h>

// HyperedgeAggregator: out[s, :] = mean over members i with segment_ids[i]==s
// of node_embeddings[node_indices[i], :].
//
// NUM_NODES=100000, EMBED_DIM=256, NUM_EDGES=16384, TOTAL=524288, seg_ids SORTED.
//
// R6 model: random-gather delivered BW is capped at ~6 TB/s CU-ingress for
// 64-B granules (measured constant across fp32/fp16/sliced variants; equals
// the HBM-copy ceiling ~6.3 TB/s). L2-locality slicing does NOT help (R5:
// better hits, slower kernel, VALU-bound). Floor = bytes gathered / 6 TB/s.
// fp16 table (268 MB gathered) is the precision-safe minimum -> agg ~48-58us.
//
//   1) prep_kernel (FUSED): fp32->fp16 table convert (unsliced row layout)
//      + seg_start[NUM_EDGES+1] bounds, one launch.
//   2) hyperedge_agg_f16_kernel (R4-proven): one wave per segment; 64-index
//      coalesced batch + __shfl broadcast; 8 independent 512-B row gathers
//      in flight; fp32 accumulate; true divide; coalesced 1 KiB row store.

#define EMBED_DIM 256
#define NUM_EDGES 16384
#define TOTAL_MEM 524288
#define NUM_NODES 100000

#define TAB16_BYTES ((size_t)NUM_NODES * EMBED_DIM * 2)         // 51,200,000
#define BOUNDS_BYTES ((size_t)(NUM_EDGES + 1) * sizeof(int))    // 65,540

#define CONV_BLOCKS   12500   // NUM_NODES*32 threads / 256  (exact)
#define BOUNDS_BLOCKS 2048    // TOTAL_MEM / 256              (exact)

// Fused: fp16 convert (unsliced) + segment bounds.
__global__ __launch_bounds__(256) void prep_kernel(
    const float4* __restrict__ emb4,      // fp32 table as float4 [NUM_NODES*64]
    uint4*        __restrict__ tab,       // fp16 table as uint4  [NUM_NODES*32]
    const int*    __restrict__ seg_ids,   // [TOTAL_MEM], sorted
    int*          __restrict__ seg_start) // [NUM_EDGES+1]
{
    const int b = blockIdx.x;
    if (b < CONV_BLOCKS) {
        const int j = b * 256 + threadIdx.x;    // [0, NUM_NODES*32): one uint4
        float4 a = emb4[2 * (size_t)j];
        float4 c = emb4[2 * (size_t)j + 1];
        __half2 h0 = __floats2half2_rn(a.x, a.y);
        __half2 h1 = __floats2half2_rn(a.z, a.w);
        __half2 h2 = __floats2half2_rn(c.x, c.y);
        __half2 h3 = __floats2half2_rn(c.z, c.w);
        uint4 o;
        o.x = *reinterpret_cast<unsigned int*>(&h0);
        o.y = *reinterpret_cast<unsigned int*>(&h1);
        o.z = *reinterpret_cast<unsigned int*>(&h2);
        o.w = *reinterpret_cast<unsigned int*>(&h3);
        tab[j] = o;
    } else {
        const int i = (b - CONV_BLOCKS) * 256 + threadIdx.x;
        if (i >= TOTAL_MEM) return;
        const int cur  = seg_ids[i];
        const int prev = (i == 0) ? -1 : seg_ids[i - 1];
        for (int s = prev + 1; s <= cur; ++s) seg_start[s] = i;
        if (i == TOTAL_MEM - 1) {
            for (int s = cur + 1; s <= NUM_EDGES; ++s) seg_start[s] = TOTAL_MEM;
        }
    }
}

// R4-proven gather kernel (unsliced fp16 rows, 512 B each).
__global__ __launch_bounds__(256) void hyperedge_agg_f16_kernel(
    const uint2* __restrict__ tab,        // fp16 table: 64 x uint2 per row
    const int*   __restrict__ node_idx,   // [TOTAL_MEM]
    const int*   __restrict__ seg_start,  // [NUM_EDGES+1]
    float*       __restrict__ out)        // [NUM_EDGES, EMBED_DIM]
{
    const int wave = threadIdx.x >> 6;           // 4 waves per block
    const int lane = threadIdx.x & 63;
    const int seg  = blockIdx.x * 4 + wave;
    if (seg >= NUM_EDGES) return;

    const int start = seg_start[seg];
    const int end   = seg_start[seg + 1];

    float4 acc = make_float4(0.f, 0.f, 0.f, 0.f);

    int i = start;
    while (i < end) {
        const int batch = min(end - i, 64);
        const int my = (lane < batch) ? node_idx[i + lane] : 0;  // coalesced

        for (int j = 0; j < batch; j += 8) {
            const int m = min(batch - j, 8);   // wave-uniform
            uint2 v[8];
            #pragma unroll
            for (int t = 0; t < 8; ++t)
                if (t < m) {
                    const int n = __shfl(my, j + t);
                    // row = 512 B; lane reads 8 B -> 64 x 8 B coalesced
                    v[t] = tab[(size_t)n * (EMBED_DIM / 4) + lane];
                }
            #pragma unroll
            for (int t = 0; t < 8; ++t)
                if (t < m) {
                    __half2 h0 = *reinterpret_cast<__half2*>(&v[t].x);
                    __half2 h1 = *reinterpret_cast<__half2*>(&v[t].y);
                    float2 f0 = __half22float2(h0);
                    float2 f1 = __half22float2(h1);
                    acc.x += f0.x; acc.y += f0.y;
                    acc.z += f1.x; acc.w += f1.y;
                }
        }
        i += batch;
    }

    const float cnt = (end > start) ? (float)(end - start) : 1.0f;
    acc.x /= cnt; acc.y /= cnt; acc.z /= cnt; acc.w /= cnt;

    ((float4*)(out + (size_t)seg * EMBED_DIM))[lane] = acc;
}

// ---------- fp32 fallback paths (small ws) ----------

__global__ __launch_bounds__(256) void seg_bounds_kernel(
    const int* __restrict__ seg_ids, int* __restrict__ seg_start)
{
    const int i = blockIdx.x * blockDim.x + threadIdx.x;
    if (i >= TOTAL_MEM) return;
    const int cur  = seg_ids[i];
    const int prev = (i == 0) ? -1 : seg_ids[i - 1];
    for (int s = prev + 1; s <= cur; ++s) seg_start[s] = i;
    if (i == TOTAL_MEM - 1) {
        for (int s = cur + 1; s <= NUM_EDGES; ++s) seg_start[s] = TOTAL_MEM;
    }
}

__global__ __launch_bounds__(256) void hyperedge_agg_kernel(
    const float* __restrict__ emb,
    const int*   __restrict__ node_idx,
    const int*   __restrict__ seg_start,
    float*       __restrict__ out)
{
    const int wave = threadIdx.x >> 6;
    const int lane = threadIdx.x & 63;
    const int seg  = blockIdx.x * 4 + wave;
    if (seg >= NUM_EDGES) return;

    const int start = seg_start[seg];
    const int end   = seg_start[seg + 1];

    float4 acc = make_float4(0.f, 0.f, 0.f, 0.f);
    int i = start;
    while (i < end) {
        const int batch = min(end - i, 64);
        const int my = (lane < batch) ? node_idx[i + lane] : 0;
        for (int j = 0; j < batch; j += 8) {
            const int mm = min(batch - j, 8);
            float4 v[8];
            #pragma unroll
            for (int t = 0; t < 8; ++t)
                if (t < mm) {
                    const int n = __shfl(my, j + t);
                    v[t] = ((const float4*)(emb + (size_t)n * EMBED_DIM))[lane];
                }
            #pragma unroll
            for (int t = 0; t < 8; ++t)
                if (t < mm) {
                    acc.x += v[t].x; acc.y += v[t].y;
                    acc.z += v[t].z; acc.w += v[t].w;
                }
        }
        i += batch;
    }
    const float cnt = (end > start) ? (float)(end - start) : 1.0f;
    acc.x /= cnt; acc.y /= cnt; acc.z /= cnt; acc.w /= cnt;
    ((float4*)(out + (size_t)seg * EMBED_DIM))[lane] = acc;
}

__global__ __launch_bounds__(256) void hyperedge_agg_bsearch_kernel(
    const float* __restrict__ emb,
    const int*   __restrict__ node_idx,
    const int*   __restrict__ seg_ids,
    float*       __restrict__ out)
{
    const int wave = threadIdx.x >> 6;
    const int lane = threadIdx.x & 63;
    const int seg  = blockIdx.x * 4 + wave;
    if (seg >= NUM_EDGES) return;

    int lo = 0, hi = TOTAL_MEM;
    while (lo < hi) {
        int mid = (lo + hi) >> 1;
        if (seg_ids[mid] < seg) lo = mid + 1; else hi = mid;
    }
    const int start = lo;
    hi = TOTAL_MEM;
    while (lo < hi) {
        int mid = (lo + hi) >> 1;
        if (seg_ids[mid] < seg + 1) lo = mid + 1; else hi = mid;
    }
    const int end = lo;

    float4 acc = make_float4(0.f, 0.f, 0.f, 0.f);
    for (int i = start; i < end; ++i) {
        const int n = node_idx[i];
        float4 v = ((const float4*)(emb + (size_t)n * EMBED_DIM))[lane];
        acc.x += v.x; acc.y += v.y; acc.z += v.z; acc.w += v.w;
    }
    const float cnt = (end > start) ? (float)(end - start) : 1.0f;
    acc.x /= cnt; acc.y /= cnt; acc.z /= cnt; acc.w /= cnt;
    ((float4*)(out + (size_t)seg * EMBED_DIM))[lane] = acc;
}

extern "C" void kernel_launch(void* const* d_in, const int* in_sizes, int n_in,
                              void* d_out, int out_size, void* d_ws, size_t ws_size,
                              hipStream_t stream) {
    const float* emb      = (const float*)d_in[0];
    const int*   node_idx = (const int*)d_in[1];
    const int*   seg_ids  = (const int*)d_in[2];
    float*       out      = (float*)d_out;

    if (ws_size >= TAB16_BYTES + BOUNDS_BYTES) {
        // Layout: [fp16 table | seg_start]
        uint4* tab16     = (uint4*)d_ws;
        int*   seg_start = (int*)((char*)d_ws + TAB16_BYTES);

        prep_kernel<<<CONV_BLOCKS + BOUNDS_BLOCKS, 256, 0, stream>>>(
            (const float4*)emb, tab16, seg_ids, seg_start);
        hyperedge_agg_f16_kernel<<<NUM_EDGES / 4, 256, 0, stream>>>(
            (const uint2*)tab16, node_idx, seg_start, out);
    } else if (ws_size >= BOUNDS_BYTES) {
        int* seg_start = (int*)d_ws;
        seg_bounds_kernel<<<(TOTAL_MEM + 255) / 256, 256, 0, stream>>>(seg_ids, seg_start);
        hyperedge_agg_kernel<<<NUM_EDGES / 4, 256, 0, stream>>>(emb, node_idx, seg_start, out);
    } else {
        hyperedge_agg_bsearch_kernel<<<NUM_EDGES / 4, 256, 0, stream>>>(emb, node_idx, seg_ids, out);
    }
}